// Round 13
// baseline (430.940 us; speedup 1.0000x reference)
//
#include <hip/hip_runtime.h>
#include <math.h>

// GAT 3-layer forward on MI355X.
// N=50000 nodes, E=850000 edges (incl self loops), IN=128, HID=OUT=32, HEADS=(4,4,6).
// GEMMs: split-f16 MFMA (hi/lo, 3 mfma), LDS-free; A and B pre-packed in MFMA-fragment
// order (pack_off) -> every wave load is 1KB contiguous. NEVER partial-unroll the tile
// loop (dynamic acc[] indexing -> scratch spill, round 4).
// Aggregation: ONE WAVE PER NODE, zero LDS, zero barriers; f16x8 (16B) gathers, 8 dims
// per lane -> 4 edge groups for ROW=128 (all 64 lanes), 2 groups for ROW=192. 4x-unrolled
// gather loop: 4 independent src->el->feat chains per lane in flight (round 12 had 2).
// All cross-lane shuffles execute unconditionally (round 9 lesson); stores guarded.
// CSR prefix scan: 3-phase multi-block (round 10's single-block scan was 77us on 1 CU).

typedef _Float16 v8h __attribute__((ext_vector_type(8)));
typedef float f32x4 __attribute__((ext_vector_type(4)));

// packed fragment offset for row n, k-dim k (128-wide K):
__device__ __host__ inline int pack_off(int n, int k) {
    return ((n >> 4) << 11) | ((k >> 5) << 9) | (((k >> 3) & 3) << 7) | ((n & 15) << 3) | (k & 7);
}

// ---------------- CSR build (by dst) ----------------

__global__ void hist_kernel(const int* __restrict__ dst, int E, int* __restrict__ deg) {
    int i = blockIdx.x * blockDim.x + threadIdx.x;
    if (i < E) atomicAdd(&deg[dst[i]], 1);
}

// ---- 3-phase exclusive scan of deg[n] -> row_start (2048 elems per block) ----

__global__ void scan_phaseA(const int* __restrict__ deg, int n, int* __restrict__ bsum) {
    __shared__ int red[4];
    int t = threadIdx.x;
    int base = blockIdx.x * 2048 + t * 8;
    int s = 0;
    #pragma unroll
    for (int q = 0; q < 8; q++) { int i = base + q; if (i < n) s += deg[i]; }
    #pragma unroll
    for (int off = 1; off < 64; off <<= 1) s += __shfl_xor(s, off);
    if ((t & 63) == 0) red[t >> 6] = s;
    __syncthreads();
    if (t == 0) bsum[blockIdx.x] = red[0] + red[1] + red[2] + red[3];
}

__global__ void scan_phaseB(int* __restrict__ bsum, int nb) {
    int lane = threadIdx.x & 63;
    int v = (lane < nb) ? bsum[lane] : 0;
    int inc = v;
    #pragma unroll
    for (int off = 1; off < 64; off <<= 1) {
        int u = __shfl_up(inc, off);
        if (lane >= off) inc += u;
    }
    int ex = inc - v;
    if (lane < nb) bsum[lane] = ex;
}

__global__ void scan_phaseC(const int* __restrict__ deg, int n, const int* __restrict__ bsum,
                            int* __restrict__ row_start, int E) {
    __shared__ int wsum[4];
    int t = threadIdx.x;
    int lane = t & 63, wv = t >> 6;
    int base = blockIdx.x * 2048 + t * 8;
    int v[8]; int s = 0;
    #pragma unroll
    for (int q = 0; q < 8; q++) { int i = base + q; v[q] = (i < n) ? deg[i] : 0; s += v[q]; }
    int inc = s;
    #pragma unroll
    for (int off = 1; off < 64; off <<= 1) {
        int u = __shfl_up(inc, off);
        if (lane >= off) inc += u;
    }
    if (lane == 63) wsum[wv] = inc;
    __syncthreads();
    int woff = 0;
    for (int w = 0; w < wv; w++) woff += wsum[w];
    int run = inc - s + woff + bsum[blockIdx.x];
    #pragma unroll
    for (int q = 0; q < 8; q++) {
        int i = base + q;
        if (i < n) row_start[i] = run;
        run += v[q];
    }
    if (blockIdx.x == 0 && t == 0) row_start[n] = E;
}

__global__ void fill_kernel(const int* __restrict__ src, const int* __restrict__ dst, int E,
                            const int* __restrict__ row_start, int* __restrict__ cursor,
                            int* __restrict__ csr_src) {
    int i = blockIdx.x * blockDim.x + threadIdx.x;
    if (i < E) {
        int d = dst[i];
        int pos = atomicAdd(&cursor[d], 1);
        csr_src[row_start[d] + pos] = src[i];
    }
}

// ---------------- weight hi/lo split into PACKED fragment layout ----------------

__global__ void wsplit_all(const float* __restrict__ W1, const float* __restrict__ W2,
                           const float* __restrict__ W3, const float* __restrict__ Wr,
                           _Float16* __restrict__ o) {
    int i = blockIdx.x * blockDim.x + threadIdx.x;
    if (i >= 81920) return;
    float v; int ohi, e, stride;
    if (i < 16384) {
        e = i; int c = e >> 7, k = e & 127;
        v = W1[(size_t)k * 128 + c]; ohi = 0; stride = 16384;
    } else if (i < 32768) {
        e = i - 16384; int c = e >> 7, k = e & 127;
        v = W2[(size_t)k * 128 + c]; ohi = 32768; stride = 16384;
    } else {
        e = i - 32768; int c = e >> 7, k = e & 127;
        v = (c < 192) ? W3[(size_t)k * 192 + c] : Wr[(size_t)k * 192 + (c - 192)];
        ohi = 65536; stride = 49152;
    }
    int c = e >> 7, k = e & 127;
    int po = pack_off(c, k);
    _Float16 hv = (_Float16)v;
    o[ohi + po] = hv;
    o[ohi + stride + po] = (_Float16)(v - (float)hv);
}

// ---------------- x -> packed hi/lo f16 fragment layout ----------------

__global__ void splitx_kernel(const float* __restrict__ x, _Float16* __restrict__ hi,
                              _Float16* __restrict__ lo, int N, int PT) {
    int i = blockIdx.x * blockDim.x + threadIdx.x;
    if (i >= PT * 2048) return;
    int mt = i >> 11, r = i & 2047;
    int q4 = r >> 9, quad = (r >> 7) & 3, ln = (r >> 3) & 15, j = r & 7;
    int n = mt * 16 + ln, k = q4 * 32 + quad * 8 + j;
    float v = (n < N) ? x[(size_t)n * 128 + k] : 0.f;
    _Float16 h = (_Float16)v;
    hi[i] = h;
    lo[i] = (_Float16)(v - (float)h);
}

// ---------------- LDS-free MFMA fc (+ attention logits), layers 1/2 ----------------

template <int CC, int H>
__global__ __launch_bounds__(256, 4) void mfma_fc(
    const _Float16* __restrict__ Ahi, const _Float16* __restrict__ Alo,
    const _Float16* __restrict__ Bhi, const _Float16* __restrict__ Blo,
    const float* __restrict__ al, const float* __restrict__ ar,
    _Float16* __restrict__ feat_out,
    float* __restrict__ el, float* __restrict__ er, int N) {
    constexpr int TILES = CC / 16;
    int t = threadIdx.x;
    int wave = t >> 6, lane = t & 63;
    int ln = lane & 15, quad = lane >> 4;
    int mt = blockIdx.x * 4 + wave;

    f32x4 acc[TILES];
    #pragma unroll
    for (int i = 0; i < TILES; i++) acc[i] = (f32x4){0.f, 0.f, 0.f, 0.f};

    const _Float16* pa_h = Ahi + (size_t)mt * 2048 + lane * 8;
    const _Float16* pa_l = Alo + (size_t)mt * 2048 + lane * 8;

    #pragma unroll
    for (int q4 = 0; q4 < 4; q4++) {
        v8h ah = *(const v8h*)(pa_h + q4 * 512);
        v8h av = *(const v8h*)(pa_l + q4 * 512);
        #pragma unroll
        for (int tt = 0; tt < TILES; tt++) {
            size_t boff = (size_t)tt * 2048 + q4 * 512 + lane * 8;
            v8h bh = *(const v8h*)(Bhi + boff);
            v8h bl = *(const v8h*)(Blo + boff);
            acc[tt] = __builtin_amdgcn_mfma_f32_16x16x32_f16(av, bh, acc[tt], 0, 0, 0);
            acc[tt] = __builtin_amdgcn_mfma_f32_16x16x32_f16(ah, bl, acc[tt], 0, 0, 0);
            acc[tt] = __builtin_amdgcn_mfma_f32_16x16x32_f16(ah, bh, acc[tt], 0, 0, 0);
        }
    }

    #pragma unroll
    for (int tt = 0; tt < TILES; tt++) {
        int n = tt * 16 + ln;
        #pragma unroll
        for (int r = 0; r < 4; r++) {
            int m = mt * 16 + quad * 4 + r;
            if (m < N) feat_out[(size_t)m * CC + n] = (_Float16)acc[tt][r];
        }
    }
    #pragma unroll
    for (int hg = 0; hg < H; hg++) {
        float a0 = al[hg * 32 + ln], a1 = al[hg * 32 + 16 + ln];
        float r0 = ar[hg * 32 + ln], r1 = ar[hg * 32 + 16 + ln];
        #pragma unroll
        for (int r = 0; r < 4; r++) {
            float pl = acc[2 * hg][r] * a0 + acc[2 * hg + 1][r] * a1;
            float pr = acc[2 * hg][r] * r0 + acc[2 * hg + 1][r] * r1;
            #pragma unroll
            for (int off = 1; off < 16; off <<= 1) {
                pl += __shfl_xor(pl, off);
                pr += __shfl_xor(pr, off);
            }
            int m = mt * 16 + quad * 4 + r;
            if (ln == 0 && m < N) {
                el[(size_t)m * H + hg] = pl;
                er[(size_t)m * H + hg] = pr;
            }
        }
    }
}

// ---------------- layer 3: dual grid (y=0: W3 feat f16 + logits; y=1: resW3 fp32) ----------------

__global__ __launch_bounds__(256, 3) void mfma_fc3(
    const _Float16* __restrict__ Ahi, const _Float16* __restrict__ Alo,
    const _Float16* __restrict__ B3h, const _Float16* __restrict__ B3l,
    const _Float16* __restrict__ Brh, const _Float16* __restrict__ Brl,
    const float* __restrict__ al, const float* __restrict__ ar,
    _Float16* __restrict__ feat_out, float* __restrict__ res_out,
    float* __restrict__ el, float* __restrict__ er, int N) {
    constexpr int CC = 192, H = 6, TILES = 12;
    const bool isres = (blockIdx.y == 1);
    const _Float16* __restrict__ Bhi = isres ? Brh : B3h;
    const _Float16* __restrict__ Blo = isres ? Brl : B3l;

    int t = threadIdx.x;
    int wave = t >> 6, lane = t & 63;
    int ln = lane & 15, quad = lane >> 4;
    int mt = blockIdx.x * 4 + wave;

    f32x4 acc[TILES];
    #pragma unroll
    for (int i = 0; i < TILES; i++) acc[i] = (f32x4){0.f, 0.f, 0.f, 0.f};

    const _Float16* pa_h = Ahi + (size_t)mt * 2048 + lane * 8;
    const _Float16* pa_l = Alo + (size_t)mt * 2048 + lane * 8;

    #pragma unroll
    for (int q4 = 0; q4 < 4; q4++) {
        v8h ah = *(const v8h*)(pa_h + q4 * 512);
        v8h av = *(const v8h*)(pa_l + q4 * 512);
        #pragma unroll
        for (int tt = 0; tt < TILES; tt++) {
            size_t boff = (size_t)tt * 2048 + q4 * 512 + lane * 8;
            v8h bh = *(const v8h*)(Bhi + boff);
            v8h bl = *(const v8h*)(Blo + boff);
            acc[tt] = __builtin_amdgcn_mfma_f32_16x16x32_f16(av, bh, acc[tt], 0, 0, 0);
            acc[tt] = __builtin_amdgcn_mfma_f32_16x16x32_f16(ah, bl, acc[tt], 0, 0, 0);
            acc[tt] = __builtin_amdgcn_mfma_f32_16x16x32_f16(ah, bh, acc[tt], 0, 0, 0);
        }
    }

    if (!isres) {
        #pragma unroll
        for (int tt = 0; tt < TILES; tt++) {
            int n = tt * 16 + ln;
            #pragma unroll
            for (int r = 0; r < 4; r++) {
                int m = mt * 16 + quad * 4 + r;
                if (m < N) feat_out[(size_t)m * CC + n] = (_Float16)acc[tt][r];
            }
        }
        #pragma unroll
        for (int hg = 0; hg < H; hg++) {
            float a0 = al[hg * 32 + ln], a1 = al[hg * 32 + 16 + ln];
            float r0 = ar[hg * 32 + ln], r1 = ar[hg * 32 + 16 + ln];
            #pragma unroll
            for (int r = 0; r < 4; r++) {
                float pl = acc[2 * hg][r] * a0 + acc[2 * hg + 1][r] * a1;
                float pr = acc[2 * hg][r] * r0 + acc[2 * hg + 1][r] * r1;
                #pragma unroll
                for (int off = 1; off < 16; off <<= 1) {
                    pl += __shfl_xor(pl, off);
                    pr += __shfl_xor(pr, off);
                }
                int m = mt * 16 + quad * 4 + r;
                if (ln == 0 && m < N) {
                    el[(size_t)m * H + hg] = pl;
                    er[(size_t)m * H + hg] = pr;
                }
            }
        }
    } else {
        #pragma unroll
        for (int tt = 0; tt < TILES; tt++) {
            int n = tt * 16 + ln;
            #pragma unroll
            for (int r = 0; r < 4; r++) {
                int m = mt * 16 + quad * 4 + r;
                if (m < N) res_out[(size_t)m * CC + n] = acc[tt][r];
            }
        }
    }
}

// ---------------- per-node aggregate: ONE WAVE PER NODE, f16x8 gathers, 4x unroll ----------------
// Lane = (edge group g, dim-octet d8). ROW=128: LPG=16, G=4. ROW=192: LPG=24, G=2.
// 4x unrolled -> 4 independent src->el->feat chains per lane (8-16 edges in flight
// per wave). All shuffles unconditional; stores guarded.
// RES: 0 none, 1 packed hi/lo, 2 plain fp32. PACK: emit packed hi/lo planes.

template <int H, bool RELU, bool MEAN, int RES, bool PACK>
__global__ __launch_bounds__(256) void gat_agg_wave(
        const _Float16* __restrict__ feat, const float* __restrict__ el,
        const float* __restrict__ er, const int* __restrict__ row_start,
        const int* __restrict__ csr_src, const float* __restrict__ bias,
        const float* __restrict__ res_plain,
        const _Float16* __restrict__ res_hi, const _Float16* __restrict__ res_lo,
        float* __restrict__ out, _Float16* __restrict__ out_hi, _Float16* __restrict__ out_lo,
        int N) {
    constexpr int ROW = H * 32;
    constexpr int LPG = ROW / 8;          // lanes per edge group (16 for H=4, 24 for H=6)
    constexpr int G   = 64 / LPG;         // edge groups (4 for H=4, 2 for H=6)
    int wv = threadIdx.x >> 6, lane = threadIdx.x & 63;
    int n = blockIdx.x * 4 + wv;
    if (n >= N) return;

    int d8 = lane % LPG;                  // dim octet: dims 8*d8 .. 8*d8+7
    int g  = lane / LPG;                  // edge group (g >= G -> idle in gather)
    int hd = d8 >> 2;                     // head of this lane's dims (4 lanes per head)

    int start = row_start[n], end = row_start[n + 1];
    float er_hd = er[(size_t)n * H + hd];
    const _Float16* fbase = feat + 8 * d8;

    float acc[8];
    #pragma unroll
    for (int q = 0; q < 8; q++) acc[q] = 0.f;
    float wsum = 0.f;

    int j = (g < G) ? (start + g) : end;
    for (; j + 3 * G < end; j += 4 * G) {
        int s0 = csr_src[j];
        int s1 = csr_src[j + G];
        int s2 = csr_src[j + 2 * G];
        int s3 = csr_src[j + 3 * G];
        float e0 = el[(size_t)s0 * H + hd] + er_hd;
        float e1 = el[(size_t)s1 * H + hd] + er_hd;
        float e2 = el[(size_t)s2 * H + hd] + er_hd;
        float e3 = el[(size_t)s3 * H + hd] + er_hd;
        v8h v0 = *(const v8h*)(fbase + (size_t)s0 * ROW);
        v8h v1 = *(const v8h*)(fbase + (size_t)s1 * ROW);
        v8h v2 = *(const v8h*)(fbase + (size_t)s2 * ROW);
        v8h v3 = *(const v8h*)(fbase + (size_t)s3 * ROW);
        e0 = (e0 >= 0.f) ? e0 : 0.2f * e0;
        e1 = (e1 >= 0.f) ? e1 : 0.2f * e1;
        e2 = (e2 >= 0.f) ? e2 : 0.2f * e2;
        e3 = (e3 >= 0.f) ? e3 : 0.2f * e3;
        float w0 = __expf(e0);
        float w1 = __expf(e1);
        float w2 = __expf(e2);
        float w3 = __expf(e3);
        wsum += (w0 + w1) + (w2 + w3);
        #pragma unroll
        for (int q = 0; q < 8; q++)
            acc[q] += (w0 * (float)v0[q] + w1 * (float)v1[q]) +
                      (w2 * (float)v2[q] + w3 * (float)v3[q]);
    }
    for (; j + G < end; j += 2 * G) {
        int s0 = csr_src[j];
        int s1 = csr_src[j + G];
        float e0 = el[(size_t)s0 * H + hd] + er_hd;
        float e1 = el[(size_t)s1 * H + hd] + er_hd;
        v8h v0 = *(const v8h*)(fbase + (size_t)s0 * ROW);
        v8h v1 = *(const v8h*)(fbase + (size_t)s1 * ROW);
        e0 = (e0 >= 0.f) ? e0 : 0.2f * e0;
        e1 = (e1 >= 0.f) ? e1 : 0.2f * e1;
        float w0 = __expf(e0);
        float w1 = __expf(e1);
        wsum += w0 + w1;
        #pragma unroll
        for (int q = 0; q < 8; q++) acc[q] += w0 * (float)v0[q] + w1 * (float)v1[q];
    }
    if (j < end) {
        int s0 = csr_src[j];
        float e0 = el[(size_t)s0 * H + hd] + er_hd;
        v8h v0 = *(const v8h*)(fbase + (size_t)s0 * ROW);
        e0 = (e0 >= 0.f) ? e0 : 0.2f * e0;
        float w0 = __expf(e0);
        wsum += w0;
        #pragma unroll
        for (int q = 0; q < 8; q++) acc[q] += w0 * (float)v0[q];
    }

    // cross-group combine (executed by ALL lanes; results valid for lanes < LPG)
    if constexpr (G == 4) {
        #pragma unroll
        for (int q = 0; q < 8; q++) {
            acc[q] += __shfl_xor(acc[q], 16);
            acc[q] += __shfl_xor(acc[q], 32);
        }
        wsum += __shfl_xor(wsum, 16);
        wsum += __shfl_xor(wsum, 32);
    } else {  // G == 2, LPG == 24: partner lane +24
        #pragma unroll
        for (int q = 0; q < 8; q++) acc[q] += __shfl(acc[q], lane + 24);
        wsum += __shfl(wsum, lane + 24);
    }

    // epilogue computed by ALL lanes; only stores guarded.
    float inv = 1.0f / fmaxf(wsum, 1e-9f);
    float4 bv0 = *(const float4*)(bias + 8 * d8);
    float4 bv1 = *(const float4*)(bias + 8 * d8 + 4);
    float r[8];
    r[0] = acc[0] * inv + bv0.x; r[1] = acc[1] * inv + bv0.y;
    r[2] = acc[2] * inv + bv0.z; r[3] = acc[3] * inv + bv0.w;
    r[4] = acc[4] * inv + bv1.x; r[5] = acc[5] * inv + bv1.y;
    r[6] = acc[6] * inv + bv1.z; r[7] = acc[7] * inv + bv1.w;

    if constexpr (RES == 1) {
        int off = pack_off(n, 8 * d8);
        v8h rh = *(const v8h*)(res_hi + off);
        v8h rl = *(const v8h*)(res_lo + off);
        #pragma unroll
        for (int q = 0; q < 8; q++) r[q] += (float)rh[q] + (float)rl[q];
    } else if constexpr (RES == 2) {
        float4 rv0 = *(const float4*)(res_plain + (size_t)n * ROW + 8 * d8);
        float4 rv1 = *(const float4*)(res_plain + (size_t)n * ROW + 8 * d8 + 4);
        r[0] += rv0.x; r[1] += rv0.y; r[2] += rv0.z; r[3] += rv0.w;
        r[4] += rv1.x; r[5] += rv1.y; r[6] += rv1.z; r[7] += rv1.w;
    }
    if constexpr (RELU) {
        #pragma unroll
        for (int q = 0; q < 8; q++) r[q] = fmaxf(r[q], 0.f);
    }

    if constexpr (PACK) {
        if (lane < LPG) {
            int off = pack_off(n, 8 * d8);
            v8h hh, ll;
            #pragma unroll
            for (int q = 0; q < 8; q++) {
                hh[q] = (_Float16)r[q];
                ll[q] = (_Float16)(r[q] - (float)hh[q]);
            }
            *(v8h*)(out_hi + off) = hh;
            *(v8h*)(out_lo + off) = ll;
        }
    } else if constexpr (MEAN) {
        // head-mean: lane d8 = h*4 + qb holds dims h*32 + 8*qb ..; writers lanes 0..3.
        int qb = d8 & 3;
        float s[8];
        #pragma unroll
        for (int q = 0; q < 8; q++) {
            s[q] = r[q];
            #pragma unroll
            for (int hh2 = 1; hh2 < H; hh2++) s[q] += __shfl(r[q], qb + 4 * hh2);
        }
        if (lane < 4) {
            const float sc = 1.0f / H;
            *(float4*)(out + (size_t)n * 32 + 8 * lane) =
                make_float4(s[0] * sc, s[1] * sc, s[2] * sc, s[3] * sc);
            *(float4*)(out + (size_t)n * 32 + 8 * lane + 4) =
                make_float4(s[4] * sc, s[5] * sc, s[6] * sc, s[7] * sc);
        }
    } else {
        if (lane < LPG) {
            *(float4*)(out + (size_t)n * ROW + 8 * d8) = make_float4(r[0], r[1], r[2], r[3]);
            *(float4*)(out + (size_t)n * ROW + 8 * d8 + 4) = make_float4(r[4], r[5], r[6], r[7]);
        }
    }
}

// ---------------- launch ----------------

extern "C" void kernel_launch(void* const* d_in, const int* in_sizes, int n_in,
                              void* d_out, int out_size, void* d_ws, size_t ws_size,
                              hipStream_t stream) {
    const float* x    = (const float*)d_in[0];
    const int*   src  = (const int*)d_in[1];
    const int*   dst  = (const int*)d_in[2];
    const float* W1   = (const float*)d_in[3];
    const float* al1  = (const float*)d_in[4];
    const float* ar1  = (const float*)d_in[5];
    const float* b1   = (const float*)d_in[6];
    const float* W2   = (const float*)d_in[7];
    const float* al2  = (const float*)d_in[8];
    const float* ar2  = (const float*)d_in[9];
    const float* b2   = (const float*)d_in[10];
    const float* W3   = (const float*)d_in[11];
    const float* al3  = (const float*)d_in[12];
    const float* ar3  = (const float*)d_in[13];
    const float* b3   = (const float*)d_in[14];
    const float* resW3= (const float*)d_in[15];
    float* out = (float*)d_out;

    const int N = in_sizes[0] / 128;
    const int E = in_sizes[1];
    const int TILES16 = (N + 15) / 16;
    const int PT = (TILES16 + 3) & ~3;
    const int NB = PT / 4;
    const int NSB = (N + 2047) / 2048;     // scan blocks (<=64 for N<=131072)

    // workspace layout
    float* fws  = (float*)d_ws;
    float* res3 = fws;                          // N*192 fp32
    float* elb  = res3 + (size_t)N * 192;       // N*6
    float* erb  = elb + (size_t)N * 6;          // N*6
    _Float16* feat_h = (_Float16*)(erb + (size_t)N * 6);  // N*192 f16
    _Float16* xh_hi  = feat_h + (size_t)N * 192;          // PT*2048 (x packed; reused as h2)
    _Float16* xh_lo  = xh_hi + (size_t)PT * 2048;
    _Float16* h1_hi  = xh_lo + (size_t)PT * 2048;
    _Float16* h1_lo  = h1_hi + (size_t)PT * 2048;
    _Float16* wts    = h1_lo + (size_t)PT * 2048;         // 163840 f16
    int* deg       = (int*)(wts + 163840);
    int* row_start = deg + N;
    int* bsum      = row_start + (N + 1);
    int* csr_src   = bsum + 64;

    const _Float16* W1h = wts;
    const _Float16* W1l = wts + 16384;
    const _Float16* W2h = wts + 32768;
    const _Float16* W2l = wts + 49152;
    const _Float16* W3h = wts + 65536;
    const _Float16* W3l = wts + 65536 + 49152;
    const _Float16* Wrh = W3h + 192 * 128;
    const _Float16* Wrl = W3l + 192 * 128;

    // ---- CSR build (by dst) + weight split + x packing ----
    hipMemsetAsync(deg, 0, (size_t)N * sizeof(int), stream);
    hist_kernel<<<dim3((E + 255) / 256), dim3(256), 0, stream>>>(dst, E, deg);
    scan_phaseA<<<dim3(NSB), dim3(256), 0, stream>>>(deg, N, bsum);
    scan_phaseB<<<dim3(1), dim3(64), 0, stream>>>(bsum, NSB);
    scan_phaseC<<<dim3(NSB), dim3(256), 0, stream>>>(deg, N, bsum, row_start, E);
    hipMemsetAsync(deg, 0, (size_t)N * sizeof(int), stream);
    fill_kernel<<<dim3((E + 255) / 256), dim3(256), 0, stream>>>(src, dst, E, row_start, deg, csr_src);
    wsplit_all<<<dim3(320), dim3(256), 0, stream>>>(W1, W2, W3, resW3, wts);
    splitx_kernel<<<dim3((PT * 2048 + 255) / 256), dim3(256), 0, stream>>>(x, xh_hi, xh_lo, N, PT);

    dim3 ab((N + 3) / 4);

    // ---- Layer 1 ----
    mfma_fc<128, 4><<<dim3(NB), dim3(256), 0, stream>>>(
        xh_hi, xh_lo, W1h, W1l, al1, ar1, feat_h, elb, erb, N);
    gat_agg_wave<4, true, false, 0, true><<<ab, dim3(256), 0, stream>>>(
        feat_h, elb, erb, row_start, csr_src, b1,
        nullptr, nullptr, nullptr, nullptr, h1_hi, h1_lo, N);

    // ---- Layer 2 (identity residual = h1 packed planes) ----
    mfma_fc<128, 4><<<dim3(NB), dim3(256), 0, stream>>>(
        h1_hi, h1_lo, W2h, W2l, al2, ar2, feat_h, elb, erb, N);
    gat_agg_wave<4, true, false, 1, true><<<ab, dim3(256), 0, stream>>>(
        feat_h, elb, erb, row_start, csr_src, b2,
        nullptr, h1_hi, h1_lo, nullptr, xh_hi, xh_lo, N);   // h2 -> reuse x planes

    // ---- Layer 3: dual GEMM, then mean-agg ----
    mfma_fc3<<<dim3(NB, 2), dim3(256), 0, stream>>>(
        xh_hi, xh_lo, W3h, W3l, Wrh, Wrl, al3, ar3, feat_h, res3, elb, erb, N);
    gat_agg_wave<6, false, true, 2, false><<<ab, dim3(256), 0, stream>>>(
        feat_h, elb, erb, row_start, csr_src, b3,
        res3, nullptr, nullptr, out, nullptr, nullptr, N);
}